// Round 1
// baseline (218.893 us; speedup 1.0000x reference)
//
#include <hip/hip_runtime.h>

#define DEV __device__ __forceinline__

namespace {

constexpr int BB = 32;      // batch
constexpr int CC = 3;       // channels
constexpr int TT = 2048;    // time
constexpr int KK = 128;     // shapelets per block
constexpr int WCHUNK = 256; // windows per workgroup
constexpr int NTHR = 256;
constexpr int OUTK = 384;   // 3 * 128
constexpr int SMEM_FLOATS = 14400; // max over instantiations (57.6 KB)

DEV float f4get(const float4 v, int j) {
  switch (j) { case 0: return v.x; case 1: return v.y; case 2: return v.z; default: return v.w; }
}

__global__ void init_out_kernel(unsigned int* out, int n) {
  int i = blockIdx.x * blockDim.x + threadIdx.x;
  if (i < n) out[i] = 0x7f800000u; // +inf bits
}

template<int S, int KT>
DEV void run_block(const float* __restrict__ x, const float* __restrict__ sh,
                   float* __restrict__ out, int b, int kh, int wchunk, int outOff,
                   float* __restrict__ smem)
{
  constexpr int W   = TT - S + 1;
  constexpr int XL  = WCHUNK + S;   // x staging length (mult of 16 floats)
  constexpr int SQn = S / 4;
  constexpr int KPW = KT / 4;       // k's owned by each wave

  float* sh_lds = smem;                       // [CC][KT][S]
  float* x_lds  = sh_lds + CC * KT * S;       // [CC][XL]
  float* x2_lds = x_lds  + CC * XL;           // [CC][WCHUNK]
  float* s2_lds = x2_lds + CC * WCHUNK;       // [CC][KT]

  const int tid = (int)threadIdx.x;
  const int w0  = wchunk * WCHUNK;

  // ---- stage shapelet tile: contiguous KT*S floats per channel, coalesced float4
  #pragma unroll
  for (int c = 0; c < CC; ++c) {
    const float4* gs = reinterpret_cast<const float4*>(sh + (size_t)(c * KK + kh * KT) * S);
    float4* ds = reinterpret_cast<float4*>(sh_lds + c * KT * S);
    #pragma unroll 1
    for (int i = tid; i < KT * S / 4; i += NTHR) ds[i] = gs[i];
  }
  // ---- stage x window (zero-fill past T)
  #pragma unroll
  for (int c = 0; c < CC; ++c) {
    const float* gx = x + (size_t)(b * CC + c) * TT;
    float* dx = x_lds + c * XL;
    #pragma unroll 1
    for (int i = tid; i < XL; i += NTHR) {
      int gi = w0 + i;
      dx[i] = (gi < TT) ? gx[gi] : 0.0f;
    }
  }
  // ---- s2 per (c,k) from global (L1/L2 hot, avoids LDS strided conflicts)
  #pragma unroll 1
  for (int i = tid; i < CC * KT; i += NTHR) {
    int c = i / KT, k = i - c * KT;
    const float* sp = sh + (size_t)(c * KK + kh * KT + k) * S;
    float acc = 0.f;
    #pragma unroll 4
    for (int s = 0; s < S; ++s) acc = fmaf(sp[s], sp[s], acc);
    s2_lds[i] = acc;
  }
  __syncthreads();

  // ---- x2 per (c,w) from LDS (stride-1 reads)
  #pragma unroll 1
  for (int i = tid; i < CC * WCHUNK; i += NTHR) {
    int c = i / WCHUNK, wi = i - c * WCHUNK;
    const float* xp = x_lds + c * XL + wi;
    float acc = 0.f;
    #pragma unroll 4
    for (int s = 0; s < S; ++s) acc = fmaf(xp[s], xp[s], acc);
    x2_lds[i] = acc;
  }
  __syncthreads();

  // ---- main loop: wave owns k-range (uniform sh reads = broadcast);
  //      lane owns 4 consecutive windows (float4 x reads)
  const int wave  = tid >> 6;
  const int lane  = tid & 63;
  const int kbase = wave * KPW;
  const float INF = __builtin_inff();

  #pragma unroll 1
  for (int kc = 0; kc < KPW / 4; ++kc) {
    const int k0 = kbase + kc * 4;
    float dsum[4][4];
    #pragma unroll
    for (int u = 0; u < 4; ++u)
      #pragma unroll
      for (int v = 0; v < 4; ++v) dsum[u][v] = 0.f;

    #pragma unroll 1
    for (int c = 0; c < CC; ++c) {
      float dot[4][4];
      #pragma unroll
      for (int u = 0; u < 4; ++u)
        #pragma unroll
        for (int v = 0; v < 4; ++v) dot[u][v] = 0.f;

      const float*  xc = x_lds + c * XL + 4 * lane;
      const float4* q0 = reinterpret_cast<const float4*>(sh_lds + (c * KT + k0 + 0) * S);
      const float4* q1 = reinterpret_cast<const float4*>(sh_lds + (c * KT + k0 + 1) * S);
      const float4* q2 = reinterpret_cast<const float4*>(sh_lds + (c * KT + k0 + 2) * S);
      const float4* q3 = reinterpret_cast<const float4*>(sh_lds + (c * KT + k0 + 3) * S);

      #pragma unroll
      for (int sq = 0; sq < SQn; ++sq) {
        float4 xa = *reinterpret_cast<const float4*>(xc + 4 * sq);
        float4 xb = *reinterpret_cast<const float4*>(xc + 4 * sq + 4);
        float xw[8] = {xa.x, xa.y, xa.z, xa.w, xb.x, xb.y, xb.z, xb.w};
        float4 s0 = q0[sq], s1 = q1[sq], s2v = q2[sq], s3 = q3[sq];
        #pragma unroll
        for (int j = 0; j < 4; ++j) {
          float a0 = f4get(s0, j), a1 = f4get(s1, j), a2 = f4get(s2v, j), a3 = f4get(s3, j);
          #pragma unroll
          for (int u = 0; u < 4; ++u) {
            float xv = xw[u + j];
            dot[u][0] = fmaf(xv, a0, dot[u][0]);
            dot[u][1] = fmaf(xv, a1, dot[u][1]);
            dot[u][2] = fmaf(xv, a2, dot[u][2]);
            dot[u][3] = fmaf(xv, a3, dot[u][3]);
          }
        }
      }

      // fold channel c into distance sum
      float4 x2q = *reinterpret_cast<const float4*>(x2_lds + c * WCHUNK + 4 * lane);
      float s20 = s2_lds[c * KT + k0 + 0];
      float s21 = s2_lds[c * KT + k0 + 1];
      float s22 = s2_lds[c * KT + k0 + 2];
      float s23 = s2_lds[c * KT + k0 + 3];
      #pragma unroll
      for (int u = 0; u < 4; ++u) {
        float x2u = f4get(x2q, u);
        dsum[u][0] += sqrtf(fmaxf(fmaf(-2.f, dot[u][0], x2u + s20), 1e-12f));
        dsum[u][1] += sqrtf(fmaxf(fmaf(-2.f, dot[u][1], x2u + s21), 1e-12f));
        dsum[u][2] += sqrtf(fmaxf(fmaf(-2.f, dot[u][2], x2u + s22), 1e-12f));
        dsum[u][3] += sqrtf(fmaxf(fmaf(-2.f, dot[u][3], x2u + s23), 1e-12f));
      }
    }

    // windowed min with validity guard
    float mv[4] = {INF, INF, INF, INF};
    #pragma unroll
    for (int u = 0; u < 4; ++u) {
      if (w0 + 4 * lane + u < W) {
        mv[0] = fminf(mv[0], dsum[u][0]);
        mv[1] = fminf(mv[1], dsum[u][1]);
        mv[2] = fminf(mv[2], dsum[u][2]);
        mv[3] = fminf(mv[3], dsum[u][3]);
      }
    }
    // cross-lane min over 64 lanes
    #pragma unroll
    for (int off = 32; off > 0; off >>= 1) {
      mv[0] = fminf(mv[0], __shfl_xor(mv[0], off));
      mv[1] = fminf(mv[1], __shfl_xor(mv[1], off));
      mv[2] = fminf(mv[2], __shfl_xor(mv[2], off));
      mv[3] = fminf(mv[3], __shfl_xor(mv[3], off));
    }
    if (lane == 0) {
      unsigned int* o = reinterpret_cast<unsigned int*>(out) + (b * OUTK + outOff + kh * KT + k0);
      atomicMin(o + 0, __float_as_uint(mv[0]));
      atomicMin(o + 1, __float_as_uint(mv[1]));
      atomicMin(o + 2, __float_as_uint(mv[2]));
      atomicMin(o + 3, __float_as_uint(mv[3]));
    }
  }
}

__global__ __launch_bounds__(NTHR) void shapelets_main(
    const float* __restrict__ x, const float* __restrict__ sh16,
    const float* __restrict__ sh32, const float* __restrict__ sh64,
    float* __restrict__ out)
{
  __shared__ float smem[SMEM_FLOATS];
  const int jx = (int)blockIdx.x;
  const int b  = (int)blockIdx.y;
  if (jx < 8) {
    run_block<16, 128>(x, sh16, out, b, 0, jx, 0, smem);
  } else if (jx < 16) {
    run_block<32, 128>(x, sh32, out, b, 0, jx - 8, 128, smem);
  } else {
    int j = jx - 16;
    run_block<64, 64>(x, sh64, out, b, j & 1, j >> 1, 256, smem);
  }
}

} // namespace

extern "C" void kernel_launch(void* const* d_in, const int* in_sizes, int n_in,
                              void* d_out, int out_size, void* d_ws, size_t ws_size,
                              hipStream_t stream) {
  const float* x    = (const float*)d_in[0];
  const float* sh16 = (const float*)d_in[1];
  const float* sh32 = (const float*)d_in[2];
  const float* sh64 = (const float*)d_in[3];
  float* out = (float*)d_out;

  const int n = BB * OUTK;
  init_out_kernel<<<(n + 255) / 256, 256, 0, stream>>>((unsigned int*)out, n);

  dim3 grid(32, BB);
  shapelets_main<<<grid, NTHR, 0, stream>>>(x, sh16, sh32, sh64, out);
}

// Round 2
// 58.924 us; speedup vs baseline: 3.7148x; 3.7148x over previous
//
#include <hip/hip_runtime.h>

typedef __attribute__((ext_vector_type(8)))  __bf16 bf16x8;
typedef __attribute__((ext_vector_type(16))) float  f32x16;

#define DEV __device__ __forceinline__

namespace {

constexpr int BB = 32, CC = 3, TT = 2048, KK = 128, NTHR = 256, OUTK = 384;
constexpr int MT = 128;          // windows per workgroup tile
constexpr int XL = 192;          // staged x length (>= MT-1+64+8 slack handled via guard)
constexpr int CPAD = 200;        // x-copy stride in elements (400 B -> bank rotation)
// LDS layout (bytes): B-frags 49152 | x bf16 copies 9600 | x rounded f32 2304 | x2 1536 | s2 1536
constexpr int OFF_XC  = 49152;
constexpr int OFF_XFR = OFF_XC + 9600;
constexpr int OFF_X2  = OFF_XFR + 2304;
constexpr int OFF_S2  = OFF_X2 + 1536;
constexpr int SMEM_BYTES = OFF_S2 + 1536;   // 64128 B

DEV unsigned short rne_bf16(float f) {
  unsigned u = __float_as_uint(f);
  u += 0x7FFFu + ((u >> 16) & 1u);
  return (unsigned short)(u >> 16);
}
DEV float bf16r_f32(float f) {  // round to nearest bf16, return as f32
  unsigned u = __float_as_uint(f);
  u += 0x7FFFu + ((u >> 16) & 1u);
  return __uint_as_float(u & 0xFFFF0000u);
}

__global__ void init_out(unsigned* o, int n) {
  int i = blockIdx.x * 256 + threadIdx.x;
  if (i < n) o[i] = 0x7f800000u;  // +inf bits
}

template<int S, int OUTOFF>
DEV void run(const float* __restrict__ x, const float* __restrict__ sh,
             unsigned* __restrict__ outu, int b, int wt, unsigned char* smem)
{
  constexpr int W      = TT - S + 1;
  constexpr int KSTEPS = S / 16;   // k-steps of 16 per MFMA
  constexpr int CHS    = S / 8;    // 8-element chunks per shapelet row

  uint4*          bl4 = (uint4*)smem;                          // frag-order B (bf16)
  unsigned short* xc  = (unsigned short*)(smem + OFF_XC);      // [CC][8][CPAD] bf16 copies
  float*          xfr = (float*)(smem + OFF_XFR);              // [CC][XL] bf16-rounded f32
  float*          x2l = (float*)(smem + OFF_X2);               // [CC][MT]
  float*          s2l = (float*)(smem + OFF_S2);               // [CC][KK]

  const int tid = (int)threadIdx.x;
  const int w0  = wt * MT;
  const float* xb = x + (size_t)(b * CC) * TT;

  // ---- 1) stage bf16-rounded x (as f32) ----
  #pragma unroll 1
  for (int i = tid; i < CC * XL; i += NTHR) {
    int c = i / XL, q = i - c * XL;
    int gi = w0 + q;
    float v = (gi < TT) ? xb[c * TT + gi] : 0.0f;
    xfr[i] = bf16r_f32(v);
  }
  // ---- 2) stage B fragments in exact lane-read order (conflict-free reads) ----
  #pragma unroll 1
  for (int i = tid; i < CC * KK * CHS; i += NTHR) {
    int c = i / (KK * CHS); int r = i - c * KK * CHS;
    int n = r / CHS;        int k0 = (r - n * CHS) * 8;
    const float* src = sh + ((size_t)(c * KK + n) * S + k0);
    unsigned short h[8];
    #pragma unroll
    for (int j = 0; j < 8; ++j) h[j] = rne_bf16(src[j]);
    uint4 d;
    d.x = (unsigned)h[0] | ((unsigned)h[1] << 16);
    d.y = (unsigned)h[2] | ((unsigned)h[3] << 16);
    d.z = (unsigned)h[4] | ((unsigned)h[5] << 16);
    d.w = (unsigned)h[6] | ((unsigned)h[7] << 16);
    int frag = (c * 4 + (n >> 5)) * KSTEPS + (k0 >> 4);
    bl4[frag * 64 + ((k0 >> 3) & 1) * 32 + (n & 31)] = d;
  }
  // ---- 3) s2 from bf16-rounded shapelets ----
  #pragma unroll 1
  for (int i = tid; i < CC * KK; i += NTHR) {
    int c = i / KK, n = i - c * KK;
    const float* sp = sh + (size_t)(c * KK + n) * S;
    float acc = 0.0f;
    #pragma unroll 4
    for (int s = 0; s < S; ++s) { float v = bf16r_f32(sp[s]); acc = fmaf(v, v, acc); }
    s2l[c * KK + n] = acc;
  }
  __syncthreads();
  // ---- 4) 8 phase-shifted bf16 copies of x (aligned b128 A-frag reads) ----
  #pragma unroll 1
  for (int i = tid; i < CC * 8 * (XL / 8); i += NTHR) {
    int c = i / (8 * (XL / 8)); int r = i - c * 8 * (XL / 8);
    int p = r / (XL / 8);       int q8 = (r - p * (XL / 8)) * 8;
    unsigned short h[8];
    #pragma unroll
    for (int j = 0; j < 8; ++j) {
      int m = q8 + j + p;  // copy_p[m'] = x[m' + p]
      float v = (m < XL) ? xfr[c * XL + m] : 0.0f;
      h[j] = (unsigned short)(__float_as_uint(v) >> 16);
    }
    uint4 d;
    d.x = (unsigned)h[0] | ((unsigned)h[1] << 16);
    d.y = (unsigned)h[2] | ((unsigned)h[3] << 16);
    d.z = (unsigned)h[4] | ((unsigned)h[5] << 16);
    d.w = (unsigned)h[6] | ((unsigned)h[7] << 16);
    ((uint4*)(xc + (size_t)(c * 8 + p) * CPAD))[q8 >> 3] = d;
  }
  // ---- 5) x2 from rounded x ----
  #pragma unroll 1
  for (int i = tid; i < CC * MT; i += NTHR) {
    int c = i / MT, w = i - c * MT;
    const float* xp = xfr + c * XL + w;
    float acc = 0.0f;
    #pragma unroll 4
    for (int s = 0; s < S; ++s) acc = fmaf(xp[s], xp[s], acc);
    x2l[i] = acc;
  }
  __syncthreads();

  // ---- main: wave (wr,wc) owns 64x64 of the 128x128 (w,k) tile ----
  const int lane = tid & 63;
  const int wv = tid >> 6;
  const int wr = wv >> 1, wc = wv & 1;
  const int l31 = lane & 31, lhi = lane >> 5;
  const int p   = lane & 7;

  f32x16 ds00{}, ds01{}, ds10{}, ds11{};

  #pragma unroll 1
  for (int c = 0; c < CC; ++c) {
    f32x16 a00{}, a01{}, a10{}, a11{};
    const unsigned short* xcb = xc + (size_t)(c * 8 + p) * CPAD;
    const int ebase = wr * 64 + l31 + lhi * 8 - p;   // multiple of 8 -> 16B aligned
    #pragma unroll
    for (int kk = 0; kk < KSTEPS; ++kk) {
      bf16x8 A0 = __builtin_bit_cast(bf16x8, *(const uint4*)(xcb + ebase + kk * 16));
      bf16x8 A1 = __builtin_bit_cast(bf16x8, *(const uint4*)(xcb + ebase + kk * 16 + 32));
      bf16x8 B0 = __builtin_bit_cast(bf16x8, bl4[((c * 4 + wc * 2 + 0) * KSTEPS + kk) * 64 + lane]);
      bf16x8 B1 = __builtin_bit_cast(bf16x8, bl4[((c * 4 + wc * 2 + 1) * KSTEPS + kk) * 64 + lane]);
      a00 = __builtin_amdgcn_mfma_f32_32x32x16_bf16(A0, B0, a00, 0, 0, 0);
      a01 = __builtin_amdgcn_mfma_f32_32x32x16_bf16(A0, B1, a01, 0, 0, 0);
      a10 = __builtin_amdgcn_mfma_f32_32x32x16_bf16(A1, B0, a10, 0, 0, 0);
      a11 = __builtin_amdgcn_mfma_f32_32x32x16_bf16(A1, B1, a11, 0, 0, 0);
    }
    const float s2c0 = s2l[c * KK + wc * 64 + l31];
    const float s2c1 = s2l[c * KK + wc * 64 + 32 + l31];
    const float* x2c = x2l + c * MT + wr * 64;
    #pragma unroll
    for (int r2 = 0; r2 < 16; ++r2) {
      const int ro = (r2 & 3) + 8 * (r2 >> 2) + 4 * lhi;  // C/D row map (m74/m101)
      const float x20 = x2c[ro];
      const float x21 = x2c[32 + ro];
      ds00[r2] += __builtin_amdgcn_sqrtf(fmaxf(fmaf(-2.0f, a00[r2], x20 + s2c0), 1e-12f));
      ds01[r2] += __builtin_amdgcn_sqrtf(fmaxf(fmaf(-2.0f, a01[r2], x20 + s2c1), 1e-12f));
      ds10[r2] += __builtin_amdgcn_sqrtf(fmaxf(fmaf(-2.0f, a10[r2], x21 + s2c0), 1e-12f));
      ds11[r2] += __builtin_amdgcn_sqrtf(fmaxf(fmaf(-2.0f, a11[r2], x21 + s2c1), 1e-12f));
    }
  }

  // ---- min over valid rows, cross-lane, atomic write ----
  const float INF = __builtin_inff();
  float m0 = INF, m1 = INF;
  #pragma unroll
  for (int r2 = 0; r2 < 16; ++r2) {
    const int ro = (r2 & 3) + 8 * (r2 >> 2) + 4 * lhi;
    if (w0 + wr * 64 + ro < W)      { m0 = fminf(m0, ds00[r2]); m1 = fminf(m1, ds01[r2]); }
    if (w0 + wr * 64 + 32 + ro < W) { m0 = fminf(m0, ds10[r2]); m1 = fminf(m1, ds11[r2]); }
  }
  m0 = fminf(m0, __shfl_xor(m0, 32));
  m1 = fminf(m1, __shfl_xor(m1, 32));
  const float mv = (lane < 32) ? m0 : m1;  // lane<32 -> cols [wc*64,+32), else [wc*64+32,+32)
  atomicMin(outu + (b * OUTK + OUTOFF + wc * 64 + lane), __float_as_uint(mv));
}

__global__ __launch_bounds__(NTHR, 2) void shapelets_mfma(
    const float* __restrict__ x, const float* __restrict__ sh16,
    const float* __restrict__ sh32, const float* __restrict__ sh64,
    unsigned* __restrict__ outu)
{
  __shared__ __attribute__((aligned(16))) unsigned char smem[SMEM_BYTES];
  const int jx = (int)blockIdx.x;
  const int b  = (int)blockIdx.y;
  if (jx < 16)      run<16,   0>(x, sh16, outu, b, jx,      smem);
  else if (jx < 32) run<32, 128>(x, sh32, outu, b, jx - 16, smem);
  else              run<64, 256>(x, sh64, outu, b, jx - 32, smem);
}

} // namespace

extern "C" void kernel_launch(void* const* d_in, const int* in_sizes, int n_in,
                              void* d_out, int out_size, void* d_ws, size_t ws_size,
                              hipStream_t stream) {
  const float* x    = (const float*)d_in[0];
  const float* sh16 = (const float*)d_in[1];
  const float* sh32 = (const float*)d_in[2];
  const float* sh64 = (const float*)d_in[3];
  unsigned* outu = (unsigned*)d_out;

  const int n = BB * OUTK;
  init_out<<<(n + 255) / 256, 256, 0, stream>>>(outu, n);

  dim3 grid(48, BB);
  shapelets_mfma<<<grid, NTHR, 0, stream>>>(x, sh16, sh32, sh64, outu);
}

// Round 4
// 47.709 us; speedup vs baseline: 4.5881x; 1.2351x over previous
//
#include <hip/hip_runtime.h>

typedef __attribute__((ext_vector_type(8)))  __bf16 bf16x8;
typedef __attribute__((ext_vector_type(16))) float  f32x16;

#define DEV __device__ __forceinline__

namespace {

constexpr int BB = 32, CC = 3, TT = 2048, KK = 128, OUTK = 384;
constexpr int TP = 2176;   // padded x-copy row length (elements)

// ---- workspace byte offsets ----
constexpr size_t OFF_B16 = 0;                       // 3*4*1*64 uint4 = 12288 B
constexpr size_t OFF_B32 = 12288;                   // 24576 B
constexpr size_t OFF_B64 = 36864;                   // 49152 B
constexpr size_t OFF_S2  = 86016;                   // [3][CC][KK] f32 = 4608 B
constexpr size_t OFF_X2  = 90624;                   // [3][BB][CC][TT] f32 = 2359296 B
constexpr size_t OFF_XC  = 2449920;                 // [BB][CC][8][TP] bf16 = 3342336 B
// total ~5.8 MB

DEV unsigned short rne(float f) {
  unsigned u = __float_as_uint(f);
  u += 0x7FFFu + ((u >> 16) & 1u);
  return (unsigned short)(u >> 16);
}
DEV float rnef(float f) {
  unsigned u = __float_as_uint(f);
  u += 0x7FFFu + ((u >> 16) & 1u);
  return __uint_as_float(u & 0xFFFF0000u);
}
DEV uint4 pack8(const unsigned short* h) {
  uint4 d;
  d.x = (unsigned)h[0] | ((unsigned)h[1] << 16);
  d.y = (unsigned)h[2] | ((unsigned)h[3] << 16);
  d.z = (unsigned)h[4] | ((unsigned)h[5] << 16);
  d.w = (unsigned)h[6] | ((unsigned)h[7] << 16);
  return d;
}

// ---------------- precompute (one shot, all conversions) ----------------
constexpr int N_OUT = BB * OUTK;            // 12288: init out to +inf
constexpr int N_BF  = 5376;                 // B-frag items (8 elems each): 768+1536+3072
constexpr int N_S2  = 1152;                 // 3*CC*KK
constexpr int N_XC  = BB * CC * 8 * (TP/8); // 208896 uint4 items
constexpr int N_X2  = BB * CC * TT;         // 196608 (computes all 3 S per thread)
constexpr int N_TOT = N_OUT + N_BF + N_S2 + N_XC + N_X2;   // 424320

__global__ __launch_bounds__(256) void precompute(
    const float* __restrict__ x, const float* __restrict__ sh16,
    const float* __restrict__ sh32, const float* __restrict__ sh64,
    unsigned char* __restrict__ ws, unsigned* __restrict__ outu)
{
  int i = blockIdx.x * 256 + threadIdx.x;
  if (i >= N_TOT) return;                    // tail guard (round-3 bug fix)
  if (i < N_OUT) { outu[i] = 0x7f800000u; return; }
  i -= N_OUT;

  if (i < N_BF) {  // shapelets -> bf16 fragments in lane-read order
    int S, it; const float* sh; size_t boff;
    if (i < 768)       { S = 16; it = i;        sh = sh16; boff = OFF_B16; }
    else if (i < 2304) { S = 32; it = i - 768;  sh = sh32; boff = OFF_B32; }
    else               { S = 64; it = i - 2304; sh = sh64; boff = OFF_B64; }
    const int CHS = S / 8, KST = S / 16;
    int c = it / (KK * CHS); int r = it - c * KK * CHS;
    int n = r / CHS;         int k0 = (r - n * CHS) * 8;
    const float* src = sh + ((size_t)(c * KK + n)) * S + k0;
    unsigned short h[8];
    #pragma unroll
    for (int j = 0; j < 8; ++j) h[j] = rne(src[j]);
    ((uint4*)(ws + boff))[((c * 4 + (n >> 5)) * KST + (k0 >> 4)) * 64 + ((k0 >> 3) & 1) * 32 + (n & 31)] = pack8(h);
    return;
  }
  i -= N_BF;

  if (i < N_S2) {  // s2 from bf16-rounded shapelets
    int Sidx = i / 384; int r = i - Sidx * 384; int c = r >> 7; int k = r & 127;
    int S = 16 << Sidx;
    const float* sh = (Sidx == 0) ? sh16 : ((Sidx == 1) ? sh32 : sh64);
    const float* sp = sh + ((size_t)(c * KK + k)) * S;
    float acc = 0.f;
    #pragma unroll 4
    for (int s = 0; s < S; ++s) { float v = rnef(sp[s]); acc = fmaf(v, v, acc); }
    ((float*)(ws + OFF_S2))[(Sidx * CC + c) * KK + k] = acc;
    return;
  }
  i -= N_S2;

  if (i < N_XC) {  // 8 phase-shifted bf16 copies of x, zero-padded
    const int per = TP / 8;                  // 272 uint4 per row
    int c8 = i / per; int q8 = i - c8 * per; // c8 = (b*CC + c)*8 + p
    int p  = c8 & 7;  int bc = c8 >> 3;
    const float* xb = x + (size_t)bc * TT;
    int m0 = q8 * 8;
    unsigned short h[8];
    #pragma unroll
    for (int j = 0; j < 8; ++j) {
      int mi = m0 + j + p;
      float v = (mi < TT) ? xb[mi] : 0.f;
      h[j] = rne(v);
    }
    ((uint4*)(ws + OFF_XC + (size_t)c8 * TP * 2))[q8] = pack8(h);
    return;
  }
  i -= N_XC;

  {  // x2 for all three S per (b,c,w), from bf16-rounded x
    int w = i & (TT - 1); int bc = i >> 11;  // bc = b*CC + c
    const float* xb = x + (size_t)bc * TT;
    float acc = 0.f, a16, a32, a64;
    #pragma unroll 4
    for (int s = 0; s < 16; ++s) { int mi = w + s; float v = (mi < TT) ? rnef(xb[mi]) : 0.f; acc = fmaf(v, v, acc); }
    a16 = acc;
    #pragma unroll 4
    for (int s = 16; s < 32; ++s) { int mi = w + s; float v = (mi < TT) ? rnef(xb[mi]) : 0.f; acc = fmaf(v, v, acc); }
    a32 = acc;
    #pragma unroll 4
    for (int s = 32; s < 64; ++s) { int mi = w + s; float v = (mi < TT) ? rnef(xb[mi]) : 0.f; acc = fmaf(v, v, acc); }
    a64 = acc;
    float* x2 = (float*)(ws + OFF_X2);
    x2[(size_t)(0 * BB * CC + bc) * TT + w] = a16;
    x2[(size_t)(1 * BB * CC + bc) * TT + w] = a32;
    x2[(size_t)(2 * BB * CC + bc) * TT + w] = a64;
  }
}

// ---------------- main: wave-independent 64w x 32k tiles ----------------
template<int S, int KST, int OUTOFF, size_t BOFF, int SIDX>
DEV void run(const unsigned char* __restrict__ ws, unsigned* __restrict__ outu,
             int b, int wt, float* __restrict__ x2l, float* __restrict__ s2l)
{
  const int tid = (int)threadIdx.x;
  const int lane = tid & 63, kq = tid >> 6;
  const int l31 = lane & 31, lhi = lane >> 5, p = l31 & 7;
  const int w0 = wt * 64;

  // tiny broadcast stage: x2 (3*64) + s2 (3*128) -> LDS
  const float* x2g = (const float*)(ws + OFF_X2) + (size_t)(SIDX * BB * CC + b * CC) * TT;
  const float* s2g = (const float*)(ws + OFF_S2) + SIDX * CC * KK;
  if (tid < 192) { int c = tid / 64, w = tid - c * 64; x2l[tid] = x2g[(size_t)c * TT + w0 + w]; }
  for (int i = tid; i < CC * KK; i += 256) s2l[i] = s2g[i];
  __syncthreads();

  const uint4* Bg = (const uint4*)(ws + BOFF);
  const unsigned short* XCb = (const unsigned short*)(ws + OFF_XC);

  f32x16 dlo{}, dhi{};
  #pragma unroll
  for (int c = 0; c < CC; ++c) {
    f32x16 alo{}, ahi{};
    const unsigned short* xcg = XCb + (size_t)((b * CC + c) * 8 + p) * TP;
    const int e0 = w0 + l31 - p + 8 * lhi;   // multiple of 8 -> 16B aligned
    #pragma unroll
    for (int kk = 0; kk < KST; ++kk) {
      bf16x8 A0 = __builtin_bit_cast(bf16x8, *(const uint4*)(xcg + e0 + 16 * kk));
      bf16x8 A1 = __builtin_bit_cast(bf16x8, *(const uint4*)(xcg + e0 + 16 * kk + 32));
      bf16x8 Bv = __builtin_bit_cast(bf16x8, Bg[((c * 4 + kq) * KST + kk) * 64 + lane]);
      alo = __builtin_amdgcn_mfma_f32_32x32x16_bf16(A0, Bv, alo, 0, 0, 0);
      ahi = __builtin_amdgcn_mfma_f32_32x32x16_bf16(A1, Bv, ahi, 0, 0, 0);
    }
    const float s2c = s2l[c * KK + kq * 32 + l31];
    const float* x2c = x2l + c * 64;
    #pragma unroll
    for (int r2 = 0; r2 < 16; ++r2) {
      const int ro = (r2 & 3) + 8 * (r2 >> 2) + 4 * lhi;  // verified C/D row map
      dlo[r2] += __builtin_amdgcn_sqrtf(fmaxf(fmaf(-2.f, alo[r2], x2c[ro] + s2c), 1e-12f));
      dhi[r2] += __builtin_amdgcn_sqrtf(fmaxf(fmaf(-2.f, ahi[r2], x2c[ro + 32] + s2c), 1e-12f));
    }
  }

  constexpr int W = TT - S + 1;
  float m = __builtin_inff();
  #pragma unroll
  for (int r2 = 0; r2 < 16; ++r2) {
    const int ro = (r2 & 3) + 8 * (r2 >> 2) + 4 * lhi;
    if (w0 + ro < W)      m = fminf(m, dlo[r2]);
    if (w0 + 32 + ro < W) m = fminf(m, dhi[r2]);
  }
  m = fminf(m, __shfl_xor(m, 32));
  if (lane < 32)
    atomicMin(outu + (b * OUTK + OUTOFF + kq * 32 + l31), __float_as_uint(m));
}

__global__ __launch_bounds__(256, 4) void shapelets_main(
    const unsigned char* __restrict__ ws, unsigned* __restrict__ outu)
{
  __shared__ float x2l[CC * 64];
  __shared__ float s2l[CC * KK];
  const int j = (int)blockIdx.x;
  const int Sidx = j % 3;             // interleave S for load balance
  const int r = j / 3;                // [0,1024)
  const int b = r >> 5, wt = r & 31;
  if (Sidx == 0)      run<16, 1,   0, OFF_B16, 0>(ws, outu, b, wt, x2l, s2l);
  else if (Sidx == 1) run<32, 2, 128, OFF_B32, 1>(ws, outu, b, wt, x2l, s2l);
  else                run<64, 4, 256, OFF_B64, 2>(ws, outu, b, wt, x2l, s2l);
}

} // namespace

extern "C" void kernel_launch(void* const* d_in, const int* in_sizes, int n_in,
                              void* d_out, int out_size, void* d_ws, size_t ws_size,
                              hipStream_t stream) {
  const float* x    = (const float*)d_in[0];
  const float* sh16 = (const float*)d_in[1];
  const float* sh32 = (const float*)d_in[2];
  const float* sh64 = (const float*)d_in[3];
  unsigned* outu = (unsigned*)d_out;
  unsigned char* ws = (unsigned char*)d_ws;

  precompute<<<(N_TOT + 255) / 256, 256, 0, stream>>>(x, sh16, sh32, sh64, ws, outu);
  shapelets_main<<<3072, 256, 0, stream>>>(ws, outu);
}